// Round 1
// baseline (1162.336 us; speedup 1.0000x reference)
//
#include <hip/hip_runtime.h>

// Problem: VectorQuantizer  M=32768 rows (32x1024), N=8192 codes, D=256, fp32.
// Outputs flat fp32: [z_out 8388608][loss 1][idx 32768]  (out_size 8421377)
// Forward math: zf=l2norm(x), cb=l2norm(emb); idx=argmin(|zf|^2-2 zf.cb+|cb|^2)
//  = argmax zf.cb ; z_out = cb[idx]; loss = 1.25*mean((cb[idx]-zf)^2)

#define M_ROWS 32768
#define N_CODES 8192
#define DIM 256

typedef short v8s __attribute__((ext_vector_type(8)));
typedef float v4f __attribute__((ext_vector_type(4)));

__device__ __forceinline__ unsigned short f2b(float f) {
    union { float f; unsigned u; } x; x.f = f;
    unsigned r = x.u + 0x7fffu + ((x.u >> 16) & 1u);   // RTNE
    return (unsigned short)(r >> 16);
}

// One wave per row: l2-normalize, emit fp32 + bf16 copies.
__global__ __launch_bounds__(256) void normalize_kernel(
        const float* __restrict__ src, float* __restrict__ dst,
        unsigned short* __restrict__ dstb, int nrows) {
    int wave = threadIdx.x >> 6, lane = threadIdx.x & 63;
    int r = blockIdx.x * 4 + wave;
    if (r >= nrows) return;
    float4 v = *(const float4*)(src + r * DIM + lane * 4);
    float ss = v.x * v.x + v.y * v.y + v.z * v.z + v.w * v.w;
    #pragma unroll
    for (int o = 32; o; o >>= 1) ss += __shfl_xor(ss, o);
    float rinv = 1.0f / fmaxf(sqrtf(ss), 1e-12f);
    float4 o4; o4.x = v.x * rinv; o4.y = v.y * rinv; o4.z = v.z * rinv; o4.w = v.w * rinv;
    *(float4*)(dst + r * DIM + lane * 4) = o4;
    ushort4 b; b.x = f2b(o4.x); b.y = f2b(o4.y); b.z = f2b(o4.z); b.w = f2b(o4.w);
    *(ushort4*)(dstb + r * DIM + lane * 4) = b;
}

// bf16 MFMA scan: each wave owns 16 query rows, scans all 8192 codes in 16-wide
// tiles (8 MFMAs of 16x16x32 per tile, K=256). Tracks top-2 per (row, code%16)
// per lane -> 32 candidates/row.
__global__ __launch_bounds__(256) void scan_kernel(
        const unsigned short* __restrict__ zfb,
        const unsigned short* __restrict__ cbb,
        int* __restrict__ cand) {
    int wave = threadIdx.x >> 6, lane = threadIdx.x & 63;
    int m = lane & 15, g = lane >> 4;
    int r0 = blockIdx.x * 64 + wave * 16;

    // A-frags: A[m][k], m=lane&15, k=32c + 8g + j
    v8s a[8];
    const v8s* ap = (const v8s*)(zfb + (r0 + m) * DIM + g * 8);
    #pragma unroll
    for (int c = 0; c < 8; ++c) a[c] = ap[c * 4];

    float b1[4], b2[4]; int i1[4], i2[4];
    #pragma unroll
    for (int q = 0; q < 4; ++q) { b1[q] = -1e30f; b2[q] = -1e30f; i1[q] = 0; i2[q] = 0; }

    const v8s* bp = (const v8s*)(cbb + m * DIM + g * 8);
    v8s bcur[8], bnxt[8];
    #pragma unroll
    for (int c = 0; c < 8; ++c) bcur[c] = bp[c * 4];

    for (int n0 = 0; n0 < N_CODES; n0 += 16) {
        // prefetch next tile (last iter reads 8KB past cbb into zf region of ws: harmless)
        #pragma unroll
        for (int c = 0; c < 8; ++c) bnxt[c] = bp[(n0 + 16) * 32 + c * 4];

        v4f acc = {0.f, 0.f, 0.f, 0.f};
        #pragma unroll
        for (int c = 0; c < 8; ++c)
            acc = __builtin_amdgcn_mfma_f32_16x16x32_bf16(a[c], bcur[c], acc, 0, 0, 0);

        int code = n0 + m;
        #pragma unroll
        for (int q = 0; q < 4; ++q) {
            float s = acc[q];
            bool gt1 = s > b1[q];
            bool gt2 = s > b2[q];
            i2[q] = gt1 ? i1[q] : (gt2 ? code : i2[q]);
            b2[q] = gt1 ? b1[q] : (gt2 ? s : b2[q]);
            i1[q] = gt1 ? code : i1[q];
            b1[q] = gt1 ? s : b1[q];
        }
        #pragma unroll
        for (int c = 0; c < 8; ++c) bcur[c] = bnxt[c];
    }
    // C/D layout: row = 4g + q, col(residue) = m
    #pragma unroll
    for (int q = 0; q < 4; ++q) {
        int row = r0 + g * 4 + q;
        int2 v; v.x = i1[q]; v.y = i2[q];
        *(int2*)(cand + row * 32 + 2 * m) = v;
    }
}

// One wave per row: exact fp64 rescore of 32 candidates, first-index tie-break,
// then emit z_out row, idx, and per-row loss partial.
__global__ __launch_bounds__(256) void rescore_kernel(
        const float* __restrict__ zf, const float* __restrict__ cb,
        const int* __restrict__ cand, float* __restrict__ out,
        float* __restrict__ out_idx, double* __restrict__ lossp) {
    int wave = threadIdx.x >> 6, lane = threadIdx.x & 63;
    int r = blockIdx.x * 4 + wave;
    float4 z4 = *(const float4*)(zf + r * DIM + lane * 4);
    double bestd = 1e300; int bestj = 0x7fffffff;
    for (int t = 0; t < 32; ++t) {
        int j = cand[r * 32 + t];
        float4 c4 = *(const float4*)(cb + j * DIM + lane * 4);
        // d = sum c*(c - 2z)  (per-row |zf|^2 constant dropped)
        double p = (double)c4.x * ((double)c4.x - 2.0 * (double)z4.x)
                 + (double)c4.y * ((double)c4.y - 2.0 * (double)z4.y)
                 + (double)c4.z * ((double)c4.z - 2.0 * (double)z4.z)
                 + (double)c4.w * ((double)c4.w - 2.0 * (double)z4.w);
        #pragma unroll
        for (int o = 32; o; o >>= 1) p += __shfl_xor(p, o);
        if (p < bestd || (p == bestd && j < bestj)) { bestd = p; bestj = j; }
    }
    float4 c4 = *(const float4*)(cb + bestj * DIM + lane * 4);
    *(float4*)(out + r * DIM + lane * 4) = c4;
    double dx = (double)c4.x - (double)z4.x, dy = (double)c4.y - (double)z4.y;
    double dz = (double)c4.z - (double)z4.z, dw = (double)c4.w - (double)z4.w;
    double lp = dx * dx + dy * dy + dz * dz + dw * dw;
    #pragma unroll
    for (int o = 32; o; o >>= 1) lp += __shfl_xor(lp, o);
    if (lane == 0) { lossp[r] = lp; out_idx[r] = (float)bestj; }
}

__global__ __launch_bounds__(256) void loss_kernel(
        const double* __restrict__ lossp, float* __restrict__ out) {
    __shared__ double sm[256];
    double s = 0.0;
    for (int i = threadIdx.x; i < M_ROWS; i += 256) s += lossp[i];
    sm[threadIdx.x] = s;
    __syncthreads();
    for (int o = 128; o; o >>= 1) {
        if ((int)threadIdx.x < o) sm[threadIdx.x] += sm[threadIdx.x + o];
        __syncthreads();
    }
    if (threadIdx.x == 0)
        out[0] = (float)(sm[0] * (1.25 / (double)(M_ROWS * DIM)));  // (BETA+1)*mean
}

extern "C" void kernel_launch(void* const* d_in, const int* in_sizes, int n_in,
                              void* d_out, int out_size, void* d_ws, size_t ws_size,
                              hipStream_t stream) {
    const float* x   = (const float*)d_in[0];   // 32*1024*256
    const float* emb = (const float*)d_in[1];   // 8192*256
    float* out = (float*)d_out;
    char* ws = (char*)d_ws;

    float*          cb   = (float*)(ws);                            // 8 MB
    unsigned short* cbb  = (unsigned short*)(ws + (8u  << 20));     // 4 MB
    float*          zf   = (float*)(ws + (12u << 20));              // 32 MB
    unsigned short* zfb  = (unsigned short*)(ws + (44u << 20));     // 16 MB
    int*            cand = (int*)(ws + (60u << 20));                // 4 MB
    double*         lossp= (double*)(ws + (64u << 20));             // 256 KB

    normalize_kernel<<<N_CODES / 4, 256, 0, stream>>>(emb, cb, cbb, N_CODES);
    normalize_kernel<<<M_ROWS / 4, 256, 0, stream>>>(x, zf, zfb, M_ROWS);
    scan_kernel<<<M_ROWS / 64, 256, 0, stream>>>(zfb, cbb, cand);
    rescore_kernel<<<M_ROWS / 4, 256, 0, stream>>>(zf, cb, cand,
                                                   out, out + (M_ROWS * DIM + 1), lossp);
    loss_kernel<<<1, 256, 0, stream>>>(lossp, out + M_ROWS * DIM);
}

// Round 2
// 845.248 us; speedup vs baseline: 1.3751x; 1.3751x over previous
//
#include <hip/hip_runtime.h>

// VectorQuantizer: M=32768 rows (32x1024), N=8192 codes, D=256, fp32.
// Outputs flat fp32: [z_out 8388608][loss 1][idx 32768]
// idx = argmax zf.cb (zf,cb l2-normalized); z_out = cb[idx];
// loss = 1.25*mean((cb[idx]-zf)^2)
//
// R2: scan restructured: 32 rows/wave (2 A-groups share B frags -> L2 B-traffic
// halved to 4GB), N-split x4 across the block's waves (occupancy + MFMA-covered
// prefetch), packed sortable-key top-2, LDS cross-slice merge. Rescore: 2-way ILP.

#define M_ROWS 32768
#define N_CODES 8192
#define DIM 256
#define SLICE 2048
#define TILES_PER_SLICE 128   // SLICE/16

typedef short v8s __attribute__((ext_vector_type(8)));
typedef float v4f __attribute__((ext_vector_type(4)));

__device__ __forceinline__ unsigned short f2b(float f) {
    union { float f; unsigned u; } x; x.f = f;
    unsigned r = x.u + 0x7fffu + ((x.u >> 16) & 1u);   // RTNE
    return (unsigned short)(r >> 16);
}
__device__ __forceinline__ unsigned umax2(unsigned a, unsigned b) { return a > b ? a : b; }
__device__ __forceinline__ unsigned umin2(unsigned a, unsigned b) { return a < b ? a : b; }

// One wave per row: l2-normalize, emit fp32 + bf16 copies.
__global__ __launch_bounds__(256) void normalize_kernel(
        const float* __restrict__ src, float* __restrict__ dst,
        unsigned short* __restrict__ dstb, int nrows) {
    int wave = threadIdx.x >> 6, lane = threadIdx.x & 63;
    int r = blockIdx.x * 4 + wave;
    if (r >= nrows) return;
    float4 v = *(const float4*)(src + r * DIM + lane * 4);
    float ss = v.x * v.x + v.y * v.y + v.z * v.z + v.w * v.w;
    #pragma unroll
    for (int o = 32; o; o >>= 1) ss += __shfl_xor(ss, o);
    float rinv = 1.0f / fmaxf(sqrtf(ss), 1e-12f);
    float4 o4; o4.x = v.x * rinv; o4.y = v.y * rinv; o4.z = v.z * rinv; o4.w = v.w * rinv;
    *(float4*)(dst + r * DIM + lane * 4) = o4;
    ushort4 b; b.x = f2b(o4.x); b.y = f2b(o4.y); b.z = f2b(o4.z); b.w = f2b(o4.w);
    *(ushort4*)(dstb + r * DIM + lane * 4) = b;
}

// Scan: block = 32 rows; wave w scans code slice [w*2048, (w+1)*2048).
// Per 16-code tile: 16 MFMAs (2 row-groups x 8 K-chunks) reusing each B-frag
// twice. Top-2 per (row, residue) kept as packed keys:
//   key = (sortable_fp32_score & ~0x1FF) | global_tile_id  (tile = code>>4)
// End: LDS merge of the 4 slices' top-2 -> 32 candidates/row.
__global__ __launch_bounds__(256) void scan_kernel(
        const unsigned short* __restrict__ zfb,
        const unsigned short* __restrict__ cbb,
        int* __restrict__ cand) {
    int tid = threadIdx.x;
    int w = tid >> 6, lane = tid & 63;
    int m = lane & 15, g = lane >> 4;
    int r0 = blockIdx.x * 32;

    // A fragments: A[m][k], k = c*32 + g*8 + j
    v8s a[2][8];
    #pragma unroll
    for (int h = 0; h < 2; ++h) {
        const v8s* ap = (const v8s*)(zfb + (r0 + h * 16 + m) * DIM + g * 8);
        #pragma unroll
        for (int c = 0; c < 8; ++c) a[h][c] = ap[c * 4];
    }

    unsigned top1[8], top2[8];
    #pragma unroll
    for (int i = 0; i < 8; ++i) { top1[i] = 0u; top2[i] = 0u; }

    const v8s* bp = (const v8s*)(cbb + (w * SLICE + m) * DIM + g * 8);
    v8s bcur[8], bnxt[8];
    #pragma unroll
    for (int c = 0; c < 8; ++c) bcur[c] = bp[c * 4];
    bp += 512;  // 16 codes * 256 shorts / 8

    int gt = w * TILES_PER_SLICE;
    for (int t = 0; t < TILES_PER_SLICE; ++t) {
        // prefetch next tile (last iter reads past slice end: discarded)
        #pragma unroll
        for (int c = 0; c < 8; ++c) bnxt[c] = bp[c * 4];
        bp += 512;

        v4f acc0 = {0.f, 0.f, 0.f, 0.f};
        v4f acc1 = {0.f, 0.f, 0.f, 0.f};
        #pragma unroll
        for (int c = 0; c < 8; ++c) {
            acc0 = __builtin_amdgcn_mfma_f32_16x16x32_bf16(a[0][c], bcur[c], acc0, 0, 0, 0);
            acc1 = __builtin_amdgcn_mfma_f32_16x16x32_bf16(a[1][c], bcur[c], acc1, 0, 0, 0);
        }

        #pragma unroll
        for (int i = 0; i < 8; ++i) {
            float s = (i < 4) ? acc0[i & 3] : acc1[i & 3];
            int su = __float_as_int(s);
            unsigned key = (unsigned)su ^ (unsigned)((su >> 31) | 0x80000000);
            key = (key & 0xFFFFFE00u) | (unsigned)gt;
            unsigned old1 = top1[i];
            top1[i] = umax2(old1, key);
            top2[i] = umax2(top2[i], umin2(old1, key));
        }
        ++gt;

        #pragma unroll
        for (int c = 0; c < 8; ++c) bcur[c] = bnxt[c];
    }

    // cross-slice merge: keys[slice][row_local][residue][pair]
    __shared__ unsigned keys[4][32][16][2];
    #pragma unroll
    for (int i = 0; i < 8; ++i) {
        int rl = (i >> 2) * 16 + g * 4 + (i & 3);   // C/D: row = g*4+q, col = m
        keys[w][rl][m][0] = top1[i];
        keys[w][rl][m][1] = top2[i];
    }
    __syncthreads();

    for (int p = tid; p < 512; p += 256) {
        int rl = p >> 4, res = p & 15;
        unsigned a1 = keys[0][rl][res][0], a2 = keys[0][rl][res][1];
        #pragma unroll
        for (int s = 1; s < 4; ++s) {
            unsigned b1 = keys[s][rl][res][0], b2 = keys[s][rl][res][1];
            unsigned n1 = umax2(a1, b1);
            unsigned n2 = umax2(umin2(a1, b1), umax2(a2, b2));
            a1 = n1; a2 = n2;
        }
        int2 v;
        v.x = (int)(a1 & 0x1FFu) * 16 + res;
        v.y = (int)(a2 & 0x1FFu) * 16 + res;
        *(int2*)(cand + (r0 + rl) * 32 + res * 2) = v;
    }
}

// One wave per row: exact fp64 rescore of 32 candidates (2-way ILP),
// first-index tie-break; emit z_out row, idx, per-row loss partial.
__global__ __launch_bounds__(256) void rescore_kernel(
        const float* __restrict__ zf, const float* __restrict__ cb,
        const int* __restrict__ cand, float* __restrict__ out,
        float* __restrict__ out_idx, double* __restrict__ lossp) {
    int wave = threadIdx.x >> 6, lane = threadIdx.x & 63;
    int r = blockIdx.x * 4 + wave;
    float4 z4 = *(const float4*)(zf + r * DIM + lane * 4);
    int call = cand[r * 32 + (lane & 31)];   // broadcast source
    double bestd = 1e300; int bestj = 0x7fffffff;
    for (int t = 0; t < 32; t += 2) {
        int j0 = __shfl(call, t);
        int j1 = __shfl(call, t + 1);
        float4 c0 = *(const float4*)(cb + j0 * DIM + lane * 4);
        float4 c1 = *(const float4*)(cb + j1 * DIM + lane * 4);
        double p0 = (double)c0.x * ((double)c0.x - 2.0 * (double)z4.x)
                  + (double)c0.y * ((double)c0.y - 2.0 * (double)z4.y)
                  + (double)c0.z * ((double)c0.z - 2.0 * (double)z4.z)
                  + (double)c0.w * ((double)c0.w - 2.0 * (double)z4.w);
        double p1 = (double)c1.x * ((double)c1.x - 2.0 * (double)z4.x)
                  + (double)c1.y * ((double)c1.y - 2.0 * (double)z4.y)
                  + (double)c1.z * ((double)c1.z - 2.0 * (double)z4.z)
                  + (double)c1.w * ((double)c1.w - 2.0 * (double)z4.w);
        #pragma unroll
        for (int o = 32; o; o >>= 1) { p0 += __shfl_xor(p0, o); p1 += __shfl_xor(p1, o); }
        if (p0 < bestd || (p0 == bestd && j0 < bestj)) { bestd = p0; bestj = j0; }
        if (p1 < bestd || (p1 == bestd && j1 < bestj)) { bestd = p1; bestj = j1; }
    }
    float4 c4 = *(const float4*)(cb + bestj * DIM + lane * 4);
    *(float4*)(out + r * DIM + lane * 4) = c4;
    double dx = (double)c4.x - (double)z4.x, dy = (double)c4.y - (double)z4.y;
    double dz = (double)c4.z - (double)z4.z, dw = (double)c4.w - (double)z4.w;
    double lp = dx * dx + dy * dy + dz * dz + dw * dw;
    #pragma unroll
    for (int o = 32; o; o >>= 1) lp += __shfl_xor(lp, o);
    if (lane == 0) { lossp[r] = lp; out_idx[r] = (float)bestj; }
}

__global__ __launch_bounds__(256) void loss_kernel(
        const double* __restrict__ lossp, float* __restrict__ out) {
    __shared__ double sm[256];
    double s = 0.0;
    for (int i = threadIdx.x; i < M_ROWS; i += 256) s += lossp[i];
    sm[threadIdx.x] = s;
    __syncthreads();
    for (int o = 128; o; o >>= 1) {
        if ((int)threadIdx.x < o) sm[threadIdx.x] += sm[threadIdx.x + o];
        __syncthreads();
    }
    if (threadIdx.x == 0)
        out[0] = (float)(sm[0] * (1.25 / (double)(M_ROWS * DIM)));  // (BETA+1)*mean
}

extern "C" void kernel_launch(void* const* d_in, const int* in_sizes, int n_in,
                              void* d_out, int out_size, void* d_ws, size_t ws_size,
                              hipStream_t stream) {
    const float* x   = (const float*)d_in[0];   // 32*1024*256
    const float* emb = (const float*)d_in[1];   // 8192*256
    float* out = (float*)d_out;
    char* ws = (char*)d_ws;

    float*          cb   = (float*)(ws);                            // 8 MB
    unsigned short* cbb  = (unsigned short*)(ws + (8u  << 20));     // 4 MB
    float*          zf   = (float*)(ws + (12u << 20));              // 32 MB
    unsigned short* zfb  = (unsigned short*)(ws + (44u << 20));     // 16 MB
    int*            cand = (int*)(ws + (60u << 20));                // 4 MB
    double*         lossp= (double*)(ws + (64u << 20));             // 256 KB

    normalize_kernel<<<N_CODES / 4, 256, 0, stream>>>(emb, cb, cbb, N_CODES);
    normalize_kernel<<<M_ROWS / 4, 256, 0, stream>>>(x, zf, zfb, M_ROWS);
    scan_kernel<<<M_ROWS / 32, 256, 0, stream>>>(zfb, cbb, cand);
    rescore_kernel<<<M_ROWS / 4, 256, 0, stream>>>(zf, cb, cand,
                                                   out, out + (M_ROWS * DIM + 1), lossp);
    loss_kernel<<<1, 256, 0, stream>>>(lossp, out + M_ROWS * DIM);
}

// Round 5
// 551.055 us; speedup vs baseline: 2.1093x; 1.5339x over previous
//
#include <hip/hip_runtime.h>

// VectorQuantizer: M=32768 rows, N=8192 codes, D=256, fp32.
// Outputs flat fp32: [z_out 8388608][loss 1][idx 32768]
// idx = argmax zf.cb (l2-normalized); z_out = cb[idx]; loss = 1.25*mean((cb[idx]-zf)^2)
//
// R5 (mechanism isolation): R3/R4 failed with ~tens of wrong rows despite the
// selection logic being R2-proven and the prune margin worst-case-proven
// (skew <= 0.017 << 0.06). Unique unvalidated delta = global_load_lds dbuf
// staging. R5 swaps it for a 3-stage VGPR pipeline (load t+2 -> regs,
// ds_write t+1, compute t) producing the IDENTICAL padded LDS image
// (CHUNK_B=1040, conflict-free reads/writes). Everything else unchanged.

#define M_ROWS 32768
#define N_CODES 8192
#define DIM 256
#define NT 256            // 16-code tiles per half
#define CHUNK_B 1040      // 2 code rows (1024B) + 16B pad (bank stagger)
#define BUF_B (8 * CHUNK_B)

typedef short v8s __attribute__((ext_vector_type(8)));
typedef float v4f __attribute__((ext_vector_type(4)));
typedef unsigned int uint;

__device__ __forceinline__ unsigned short f2b(float f) {
    union { float f; unsigned u; } x; x.f = f;
    unsigned r = x.u + 0x7fffu + ((x.u >> 16) & 1u);   // RTNE
    return (unsigned short)(r >> 16);
}
__device__ __forceinline__ uint umax2(uint a, uint b) { return a > b ? a : b; }
__device__ __forceinline__ uint umin2(uint a, uint b) { return a < b ? a : b; }

// One wave per row: l2-normalize; emit fp32 (optional) + bf16 copies.
__global__ __launch_bounds__(256) void normalize_kernel(
        const float* __restrict__ src, float* __restrict__ dst,
        unsigned short* __restrict__ dstb, int nrows) {
    int wave = threadIdx.x >> 6, lane = threadIdx.x & 63;
    int r = blockIdx.x * 4 + wave;
    if (r >= nrows) return;
    float4 v = *(const float4*)(src + (size_t)r * DIM + lane * 4);
    float ss = v.x * v.x + v.y * v.y + v.z * v.z + v.w * v.w;
    #pragma unroll
    for (int o = 32; o; o >>= 1) ss += __shfl_xor(ss, o);
    float rinv = 1.0f / fmaxf(sqrtf(ss), 1e-12f);
    float4 o4; o4.x = v.x * rinv; o4.y = v.y * rinv; o4.z = v.z * rinv; o4.w = v.w * rinv;
    if (dst) *(float4*)(dst + (size_t)r * DIM + lane * 4) = o4;
    ushort4 b; b.x = f2b(o4.x); b.y = f2b(o4.y); b.z = f2b(o4.z); b.w = f2b(o4.w);
    *(ushort4*)(dstb + (size_t)r * DIM + lane * 4) = b;
}

// Scan: block = 128 rows x one half (4096 codes). Wave w owns rows [w*32,+32).
// B staged to LDS through VGPRs (3-stage pipeline), double-buffered, one
// barrier per 16-code tile. LDS image: chunk q (= code rows {2q,2q+1}) at
// q*CHUNK_B, byte i of the 1024 at chunk_base + i (identity within chunk).
// Per tile: 8 ds_read_b128 -> 16 MFMA (2 row groups share each B frag).
// Top-2 keys per (row,residue): key = fp32bits(score+2) & ~0x1FF | tile9.
__global__ __launch_bounds__(256, 2) void scan_kernel(
        const unsigned short* __restrict__ zfb,
        const unsigned short* __restrict__ cbb,
        uint* __restrict__ cand) {   // [row][64] = [row][2half][16res][2]
    __shared__ __align__(16) char lds[2 * BUF_B];
    int tid = threadIdx.x, w = tid >> 6, lane = tid & 63;
    int m = lane & 15, g = lane >> 4;
    int rb = blockIdx.x >> 1, half = blockIdx.x & 1;
    int r0 = rb * 128 + w * 32;

    // A fragments: A[m][k], k = c*32 + g*8 + j
    v8s a[2][8];
    #pragma unroll
    for (int h = 0; h < 2; ++h) {
        const unsigned short* ap = zfb + (size_t)(r0 + h * 16 + m) * DIM + g * 8;
        #pragma unroll
        for (int c = 0; c < 8; ++c) a[h][c] = *(const v8s*)(ap + c * 32);
    }

    // Staging addresses: part i in {0,1} -> chunk q = 2w+i.
    const char* cb_base = (const char*)cbb + (size_t)half * 4096 * 512;
    const char* gp[2];
    int wo[2];
    #pragma unroll
    for (int i = 0; i < 2; ++i) {
        int q = 2 * w + i;
        gp[i] = cb_base + q * 1024 + lane * 16;
        wo[i] = q * CHUNK_B + lane * 16;
    }
    // ds_read byte offsets per K-chunk c: tile-row m, 16B unit (4c+g)
    int roff[8];
    #pragma unroll
    for (int c = 0; c < 8; ++c)
        roff[c] = (m >> 1) * CHUNK_B + (m & 1) * 512 + (4 * c + g) * 16;

    // 3-stage pipeline prologue: load tile0 -> write buf0 -> load tile1
    uint4 st[2];
    #pragma unroll
    for (int i = 0; i < 2; ++i) { st[i] = *(const uint4*)gp[i]; gp[i] += 8192; }
    #pragma unroll
    for (int i = 0; i < 2; ++i) *(uint4*)(lds + wo[i]) = st[i];
    #pragma unroll
    for (int i = 0; i < 2; ++i) { st[i] = *(const uint4*)gp[i]; gp[i] += 8192; }

    uint top1[8], top2[8];
    #pragma unroll
    for (int i = 0; i < 8; ++i) { top1[i] = 0u; top2[i] = 0u; }

    for (int t = 0; t < NT; ++t) {
        __syncthreads();   // drains own ds_write/ds_read/loads; tile t visible
        if (t + 1 < NT) {
            char* nbuf = lds + ((t + 1) & 1) * BUF_B;
            #pragma unroll
            for (int i = 0; i < 2; ++i) *(uint4*)(nbuf + wo[i]) = st[i];
            if (t + 2 < NT) {
                #pragma unroll
                for (int i = 0; i < 2; ++i) { st[i] = *(const uint4*)gp[i]; gp[i] += 8192; }
            }
        }
        const char* cbuf = lds + (t & 1) * BUF_B;
        v4f aA0 = {2.f, 2.f, 2.f, 2.f}, aB0 = {0.f, 0.f, 0.f, 0.f};
        v4f aA1 = {2.f, 2.f, 2.f, 2.f}, aB1 = {0.f, 0.f, 0.f, 0.f};
        #pragma unroll
        for (int c = 0; c < 8; ++c) {
            v8s b = *(const v8s*)(cbuf + roff[c]);
            if (c & 1) {
                aB0 = __builtin_amdgcn_mfma_f32_16x16x32_bf16(a[0][c], b, aB0, 0, 0, 0);
                aB1 = __builtin_amdgcn_mfma_f32_16x16x32_bf16(a[1][c], b, aB1, 0, 0, 0);
            } else {
                aA0 = __builtin_amdgcn_mfma_f32_16x16x32_bf16(a[0][c], b, aA0, 0, 0, 0);
                aA1 = __builtin_amdgcn_mfma_f32_16x16x32_bf16(a[1][c], b, aA1, 0, 0, 0);
            }
        }
        uint gt = (uint)(half * NT + t);   // 9-bit global tile id
        #pragma unroll
        for (int i = 0; i < 8; ++i) {
            float s = (i < 4) ? (aA0[i & 3] + aB0[i & 3]) : (aA1[i & 3] + aB1[i & 3]);
            uint key = (__float_as_uint(s) & 0xFFFFFE00u) | gt;  // s+2 in [1,3]: sortable
            uint old1 = top1[i];
            top1[i] = umax2(old1, key);
            top2[i] = umax2(top2[i], umin2(old1, key));
        }
    }

    // C/D layout: row = g*4 + q, col(residue) = m
    #pragma unroll
    for (int i = 0; i < 8; ++i) {
        int h = i >> 2, q = i & 3;
        int row = r0 + h * 16 + g * 4 + q;
        uint2 v; v.x = top1[i]; v.y = top2[i];
        *(uint2*)(cand + (size_t)row * 64 + (half * 16 + m) * 2) = v;
    }
}

// One wave per row: prune 64 candidates by key margin (0.06 > worst-case bf16
// skew ~0.017), fp64-rescore survivors (first-index tie-break); emit z_out,
// idx, per-row loss partial.
__global__ __launch_bounds__(256) void rescore_kernel(
        const float* __restrict__ x, const float* __restrict__ cb,
        const uint* __restrict__ cand, float* __restrict__ out,
        float* __restrict__ out_idx, double* __restrict__ lossp) {
    int wave = threadIdx.x >> 6, lane = threadIdx.x & 63;
    int r = blockIdx.x * 4 + wave;
    float4 xv = *(const float4*)(x + (size_t)r * DIM + lane * 4);
    float ss = xv.x * xv.x + xv.y * xv.y + xv.z * xv.z + xv.w * xv.w;
    #pragma unroll
    for (int o = 32; o; o >>= 1) ss += __shfl_xor(ss, o);
    float rinv = 1.0f / fmaxf(sqrtf(ss), 1e-12f);
    float4 z4; z4.x = xv.x * rinv; z4.y = xv.y * rinv; z4.z = xv.z * rinv; z4.w = xv.w * rinv;

    uint k = cand[(size_t)r * 64 + lane];
    float kf = __uint_as_float(k & 0xFFFFFE00u);
    float kmax = kf;
    #pragma unroll
    for (int o = 32; o; o >>= 1) kmax = fmaxf(kmax, __shfl_xor(kmax, o));
    bool pred = kf >= kmax - 0.060f;
    unsigned long long mask = __ballot(pred);
    int code = (int)(k & 0x1FFu) * 16 + ((lane >> 1) & 15);

    double bestd = 1e300; int bestj = 0x7fffffff;
    while (mask) {
        int b = __builtin_ctzll(mask); mask &= mask - 1;
        int j = __shfl(code, b);
        float4 c4 = *(const float4*)(cb + (size_t)j * DIM + lane * 4);
        double p = (double)c4.x * ((double)c4.x - 2.0 * (double)z4.x)
                 + (double)c4.y * ((double)c4.y - 2.0 * (double)z4.y)
                 + (double)c4.z * ((double)c4.z - 2.0 * (double)z4.z)
                 + (double)c4.w * ((double)c4.w - 2.0 * (double)z4.w);
        #pragma unroll
        for (int o = 32; o; o >>= 1) p += __shfl_xor(p, o);
        if (p < bestd || (p == bestd && j < bestj)) { bestd = p; bestj = j; }
    }
    float4 c4 = *(const float4*)(cb + (size_t)bestj * DIM + lane * 4);
    *(float4*)(out + (size_t)r * DIM + lane * 4) = c4;
    double dx = (double)c4.x - (double)z4.x, dy = (double)c4.y - (double)z4.y;
    double dz = (double)c4.z - (double)z4.z, dw = (double)c4.w - (double)z4.w;
    double lp = dx * dx + dy * dy + dz * dz + dw * dw;
    #pragma unroll
    for (int o = 32; o; o >>= 1) lp += __shfl_xor(lp, o);
    if (lane == 0) { lossp[r] = lp; out_idx[r] = (float)bestj; }
}

__global__ __launch_bounds__(256) void loss_kernel(
        const double* __restrict__ lossp, float* __restrict__ out) {
    __shared__ double sm[256];
    double s = 0.0;
    for (int i = threadIdx.x; i < M_ROWS; i += 256) s += lossp[i];
    sm[threadIdx.x] = s;
    __syncthreads();
    for (int o = 128; o; o >>= 1) {
        if ((int)threadIdx.x < o) sm[threadIdx.x] += sm[threadIdx.x + o];
        __syncthreads();
    }
    if (threadIdx.x == 0)
        out[0] = (float)(sm[0] * (1.25 / (double)(M_ROWS * DIM)));  // (BETA+1)*mean
}

extern "C" void kernel_launch(void* const* d_in, const int* in_sizes, int n_in,
                              void* d_out, int out_size, void* d_ws, size_t ws_size,
                              hipStream_t stream) {
    const float* x   = (const float*)d_in[0];   // 32*1024*256
    const float* emb = (const float*)d_in[1];   // 8192*256
    float* out = (float*)d_out;
    char* ws = (char*)d_ws;

    float*          cb    = (float*)(ws);                          // 8 MB
    unsigned short* cbb   = (unsigned short*)(ws + (8u  << 20));   // 4 MB
    unsigned short* zfb   = (unsigned short*)(ws + (12u << 20));   // 16 MB
    uint*           cand  = (uint*)(ws + (28u << 20));             // 8 MB
    double*         lossp = (double*)(ws + (36u << 20));           // 256 KB

    normalize_kernel<<<N_CODES / 4, 256, 0, stream>>>(emb, cb, cbb, N_CODES);
    normalize_kernel<<<M_ROWS / 4, 256, 0, stream>>>(x, nullptr, zfb, M_ROWS);
    scan_kernel<<<512, 256, 0, stream>>>(zfb, cbb, cand);
    rescore_kernel<<<M_ROWS / 4, 256, 0, stream>>>(x, cb, cand,
                                                   out, out + ((size_t)M_ROWS * DIM + 1), lossp);
    loss_kernel<<<1, 256, 0, stream>>>(lossp, out + (size_t)M_ROWS * DIM);
}

// Round 6
// 406.672 us; speedup vs baseline: 2.8582x; 1.3550x over previous
//
#include <hip/hip_runtime.h>

// VectorQuantizer: M=32768 rows, N=8192 codes, D=256, fp32.
// Outputs flat fp32: [z_out 8388608][loss 1][idx 32768]
// idx = argmax zf.cb (l2-normalized); z_out = cb[idx]; loss = 1.25*mean((cb[idx]-zf)^2)
//
// R6: scan intensity doubled: 64 rows/wave (4 A-groups share each B frag),
// quarter code split per block (512 blocks, 8 waves/CU). LDS XOR-swizzle
// (unit u of row r at r*512+((u&24)|((u^r)&7))*16) kills the 5e7 bank-conflict
// cycles R5 measured. Staging stays the R5-proven VGPR 3-stage pipeline.
// Rescore: single-survivor fast path (margin 0.05 >= 2.5x worst-case bf16 skew
// 0.0196 -> unique survivor is provably the exact argmax, no fp64 needed).

#define M_ROWS 32768
#define N_CODES 8192
#define DIM 256
#define NTQ 128           // 16-code tiles per quarter (2048 codes)
#define BUF_B 8192        // 16 code rows * 512B

typedef short v8s __attribute__((ext_vector_type(8)));
typedef float v4f __attribute__((ext_vector_type(4)));
typedef unsigned int uint;

__device__ __forceinline__ unsigned short f2b(float f) {
    union { float f; unsigned u; } x; x.f = f;
    unsigned r = x.u + 0x7fffu + ((x.u >> 16) & 1u);   // RTNE
    return (unsigned short)(r >> 16);
}
__device__ __forceinline__ uint umax2(uint a, uint b) { return a > b ? a : b; }
__device__ __forceinline__ uint umin2(uint a, uint b) { return a < b ? a : b; }
__device__ __forceinline__ int swz(int u, int r) {    // 16B-unit XOR swizzle
    return (u & 24) | ((u ^ r) & 7);
}

// One wave per row: l2-normalize; emit fp32 (optional) + bf16 copies.
__global__ __launch_bounds__(256) void normalize_kernel(
        const float* __restrict__ src, float* __restrict__ dst,
        unsigned short* __restrict__ dstb, int nrows) {
    int wave = threadIdx.x >> 6, lane = threadIdx.x & 63;
    int r = blockIdx.x * 4 + wave;
    if (r >= nrows) return;
    float4 v = *(const float4*)(src + (size_t)r * DIM + lane * 4);
    float ss = v.x * v.x + v.y * v.y + v.z * v.z + v.w * v.w;
    #pragma unroll
    for (int o = 32; o; o >>= 1) ss += __shfl_xor(ss, o);
    float rinv = 1.0f / fmaxf(sqrtf(ss), 1e-12f);
    float4 o4; o4.x = v.x * rinv; o4.y = v.y * rinv; o4.z = v.z * rinv; o4.w = v.w * rinv;
    if (dst) *(float4*)(dst + (size_t)r * DIM + lane * 4) = o4;
    ushort4 b; b.x = f2b(o4.x); b.y = f2b(o4.y); b.z = f2b(o4.z); b.w = f2b(o4.w);
    *(ushort4*)(dstb + (size_t)r * DIM + lane * 4) = b;
}

// Scan: block = 256 rows x one quarter (2048 codes). Wave w owns rows
// [w*64, w*64+64) as 4 MFMA row-groups; all 4 share each B fragment
// (8 ds_read_b128 -> 32 MFMA per 16-code tile). B staged to LDS through VGPRs
// (3-stage pipeline, double buffer, 1 barrier/tile), XOR-swizzled layout.
// Top-2 keys per (row, residue16): key = fp32bits(score+2) & ~0x1FF | tile9.
__global__ __launch_bounds__(256, 2) void scan_kernel(
        const unsigned short* __restrict__ zfb,
        const unsigned short* __restrict__ cbb,
        uint* __restrict__ cand) {   // [row][128] = [row][4quarter][16res][2]
    __shared__ __align__(16) char lds[2 * BUF_B];
    int tid = threadIdx.x, w = tid >> 6, lane = tid & 63;
    int m = lane & 15, g = lane >> 4;
    int rb = blockIdx.x >> 2, quarter = blockIdx.x & 3;
    int r0 = rb * 256 + w * 64;

    // A fragments: A[m][k], k = c*32 + g*8 + j ; 4 row-groups of 16
    v8s a[4][8];
    #pragma unroll
    for (int h = 0; h < 4; ++h) {
        const unsigned short* ap = zfb + (size_t)(r0 + h * 16 + m) * DIM + g * 8;
        #pragma unroll
        for (int c = 0; c < 8; ++c) a[h][c] = *(const v8s*)(ap + c * 32);
    }

    // Staging: part i -> chunk q = 2w+i = code-row pair {2q, 2q+1}.
    const char* cb_base = (const char*)cbb + (size_t)quarter * 2048 * 512;
    const char* gp[2];
    int wo[2];
    #pragma unroll
    for (int i = 0; i < 2; ++i) {
        int q = 2 * w + i;
        int rr = 2 * q + (lane >> 5);
        int u = lane & 31;
        gp[i] = cb_base + q * 1024 + lane * 16;
        wo[i] = rr * 512 + swz(u, rr) * 16;
    }
    // ds_read offsets per K-chunk c: tile-row m, logical unit (4c+g), swizzled
    int roff[8];
    #pragma unroll
    for (int c = 0; c < 8; ++c)
        roff[c] = m * 512 + swz(4 * c + g, m) * 16;

    // 3-stage pipeline prologue: load tile0 -> write buf0 -> load tile1
    uint4 st[2];
    #pragma unroll
    for (int i = 0; i < 2; ++i) { st[i] = *(const uint4*)gp[i]; gp[i] += 8192; }
    #pragma unroll
    for (int i = 0; i < 2; ++i) *(uint4*)(lds + wo[i]) = st[i];
    #pragma unroll
    for (int i = 0; i < 2; ++i) { st[i] = *(const uint4*)gp[i]; gp[i] += 8192; }

    uint top1[16], top2[16];
    #pragma unroll
    for (int i = 0; i < 16; ++i) { top1[i] = 0u; top2[i] = 0u; }

    for (int t = 0; t < NTQ; ++t) {
        __syncthreads();   // all waves' writes of tile t visible; reads of t-1 done
        if (t + 1 < NTQ) {
            char* nbuf = lds + ((t + 1) & 1) * BUF_B;
            #pragma unroll
            for (int i = 0; i < 2; ++i) *(uint4*)(nbuf + wo[i]) = st[i];
            if (t + 2 < NTQ) {
                #pragma unroll
                for (int i = 0; i < 2; ++i) { st[i] = *(const uint4*)gp[i]; gp[i] += 8192; }
            }
        }
        const char* cbuf = lds + (t & 1) * BUF_B;
        v4f acc[4];
        #pragma unroll
        for (int h = 0; h < 4; ++h) acc[h] = (v4f){2.f, 2.f, 2.f, 2.f};
        #pragma unroll
        for (int c = 0; c < 8; ++c) {
            v8s b = *(const v8s*)(cbuf + roff[c]);
            #pragma unroll
            for (int h = 0; h < 4; ++h)
                acc[h] = __builtin_amdgcn_mfma_f32_16x16x32_bf16(a[h][c], b, acc[h], 0, 0, 0);
        }
        uint gt = (uint)(quarter * NTQ + t);   // 9-bit global tile id
        #pragma unroll
        for (int i = 0; i < 16; ++i) {
            float s = acc[i >> 2][i & 3];      // s in [1,3]: bits sortable
            uint key = (__float_as_uint(s) & 0xFFFFFE00u) | gt;
            uint old1 = top1[i];
            top1[i] = umax2(old1, key);
            top2[i] = umax2(top2[i], umin2(old1, key));
        }
    }

    // C/D layout: row = g*4 + q, col(residue) = m
    #pragma unroll
    for (int i = 0; i < 16; ++i) {
        int h = i >> 2, q = i & 3;
        int row = r0 + h * 16 + g * 4 + q;
        uint2 v; v.x = top1[i]; v.y = top2[i];
        *(uint2*)(cand + (size_t)row * 128 + (quarter * 16 + m) * 2) = v;
    }
}

// One wave per row: 128 candidate keys (uint2/lane). Prune at margin 0.05
// (worst-case bf16 key skew: 2*2^-8*sum|ab| + trunc <= 0.0196). If exactly one
// survivor, it is provably the exact argmax (fast path, no fp64). Else fp64
// rescore survivors, first-index tie-break. Emit z_out, idx, loss partial.
__global__ __launch_bounds__(256) void rescore_kernel(
        const float* __restrict__ x, const float* __restrict__ cb,
        const uint* __restrict__ cand, float* __restrict__ out,
        float* __restrict__ out_idx, double* __restrict__ lossp) {
    int wave = threadIdx.x >> 6, lane = threadIdx.x & 63;
    int r = blockIdx.x * 4 + wave;
    float4 xv = *(const float4*)(x + (size_t)r * DIM + lane * 4);
    float ss = xv.x * xv.x + xv.y * xv.y + xv.z * xv.z + xv.w * xv.w;
    #pragma unroll
    for (int o = 32; o; o >>= 1) ss += __shfl_xor(ss, o);
    float rinv = 1.0f / fmaxf(sqrtf(ss), 1e-12f);
    float4 z4; z4.x = xv.x * rinv; z4.y = xv.y * rinv; z4.z = xv.z * rinv; z4.w = xv.w * rinv;

    uint2 kk = *(const uint2*)(cand + (size_t)r * 128 + lane * 2);
    float kf0 = __uint_as_float(kk.x & 0xFFFFFE00u);
    float kf1 = __uint_as_float(kk.y & 0xFFFFFE00u);
    float kmax = fmaxf(kf0, kf1);
    #pragma unroll
    for (int o = 32; o; o >>= 1) kmax = fmaxf(kmax, __shfl_xor(kmax, o));
    float thr = kmax - 0.050f;
    unsigned long long m0 = __ballot(kf0 >= thr);
    unsigned long long m1 = __ballot(kf1 >= thr);
    int code0 = (int)(kk.x & 0x1FFu) * 16 + (lane & 15);
    int code1 = (int)(kk.y & 0x1FFu) * 16 + (lane & 15);

    int bestj;
    if (__popcll(m0) + __popcll(m1) == 1) {
        // unique survivor == exact argmax (margin covers worst-case bf16 skew)
        bestj = m0 ? __shfl(code0, (int)__builtin_ctzll(m0))
                   : __shfl(code1, (int)__builtin_ctzll(m1));
    } else {
        double bestd = 1e300; bestj = 0x7fffffff;
        #pragma unroll
        for (int half = 0; half < 2; ++half) {
            unsigned long long mask = half ? m1 : m0;
            int codes = half ? code1 : code0;
            while (mask) {
                int b = (int)__builtin_ctzll(mask); mask &= mask - 1;
                int j = __shfl(codes, b);
                float4 c4 = *(const float4*)(cb + (size_t)j * DIM + lane * 4);
                double p = (double)c4.x * ((double)c4.x - 2.0 * (double)z4.x)
                         + (double)c4.y * ((double)c4.y - 2.0 * (double)z4.y)
                         + (double)c4.z * ((double)c4.z - 2.0 * (double)z4.z)
                         + (double)c4.w * ((double)c4.w - 2.0 * (double)z4.w);
                #pragma unroll
                for (int o = 32; o; o >>= 1) p += __shfl_xor(p, o);
                if (p < bestd || (p == bestd && j < bestj)) { bestd = p; bestj = j; }
            }
        }
    }
    float4 c4 = *(const float4*)(cb + (size_t)bestj * DIM + lane * 4);
    *(float4*)(out + (size_t)r * DIM + lane * 4) = c4;
    double dx = (double)c4.x - (double)z4.x, dy = (double)c4.y - (double)z4.y;
    double dz = (double)c4.z - (double)z4.z, dw = (double)c4.w - (double)z4.w;
    double lp = dx * dx + dy * dy + dz * dz + dw * dw;
    #pragma unroll
    for (int o = 32; o; o >>= 1) lp += __shfl_xor(lp, o);
    if (lane == 0) { lossp[r] = lp; out_idx[r] = (float)bestj; }
}

__global__ __launch_bounds__(256) void loss_kernel(
        const double* __restrict__ lossp, float* __restrict__ out) {
    __shared__ double sm[256];
    double s = 0.0;
    for (int i = threadIdx.x; i < M_ROWS; i += 256) s += lossp[i];
    sm[threadIdx.x] = s;
    __syncthreads();
    for (int o = 128; o; o >>= 1) {
        if ((int)threadIdx.x < o) sm[threadIdx.x] += sm[threadIdx.x + o];
        __syncthreads();
    }
    if (threadIdx.x == 0)
        out[0] = (float)(sm[0] * (1.25 / (double)(M_ROWS * DIM)));  // (BETA+1)*mean
}

extern "C" void kernel_launch(void* const* d_in, const int* in_sizes, int n_in,
                              void* d_out, int out_size, void* d_ws, size_t ws_size,
                              hipStream_t stream) {
    const float* x   = (const float*)d_in[0];   // 32*1024*256
    const float* emb = (const float*)d_in[1];   // 8192*256
    float* out = (float*)d_out;
    char* ws = (char*)d_ws;

    float*          cb    = (float*)(ws);                          // 8 MB
    unsigned short* cbb   = (unsigned short*)(ws + (8u  << 20));   // 4 MB
    unsigned short* zfb   = (unsigned short*)(ws + (12u << 20));   // 16 MB
    uint*           cand  = (uint*)(ws + (28u << 20));             // 16 MB
    double*         lossp = (double*)(ws + (44u << 20));           // 256 KB

    normalize_kernel<<<N_CODES / 4, 256, 0, stream>>>(emb, cb, cbb, N_CODES);
    normalize_kernel<<<M_ROWS / 4, 256, 0, stream>>>(x, nullptr, zfb, M_ROWS);
    scan_kernel<<<512, 256, 0, stream>>>(zfb, cbb, cand);
    rescore_kernel<<<M_ROWS / 4, 256, 0, stream>>>(x, cb, cand,
                                                   out, out + ((size_t)M_ROWS * DIM + 1), lossp);
    loss_kernel<<<1, 256, 0, stream>>>(lossp, out + (size_t)M_ROWS * DIM);
}

// Round 7
// 397.304 us; speedup vs baseline: 2.9256x; 1.0236x over previous
//
#include <hip/hip_runtime.h>

// VectorQuantizer: M=32768 rows, N=8192 codes, D=256, fp32.
// Outputs flat fp32: [z_out 8388608][loss 1][idx 32768]
// idx = argmax zf.cb (l2-normalized); z_out = cb[idx]; loss = 1.25*mean((cb[idx]-zf)^2)
//
// R7: scan VALU diet (acc init via MFMA C=const2 -> no movs; and_or key combine;
// 32-code tiles -> half the barriers). Rescore rewritten lane-parallel: survivors
// compacted via ballot-prefix into LDS, one fp32 dot per lane, fp64 only for
// fp32-near-ties (2e-4 margin >> fp32 dot error 5e-6; unique-near => exact).

#define M_ROWS 32768
#define N_CODES 8192
#define DIM 256
#define NT 64             // 32-code tiles per quarter (2048 codes)
#define BUF_B 16384       // 32 code rows * 512B

typedef short v8s __attribute__((ext_vector_type(8)));
typedef float v4f __attribute__((ext_vector_type(4)));
typedef unsigned int uint;
typedef unsigned long long ull;

__device__ __forceinline__ unsigned short f2b(float f) {
    union { float f; unsigned u; } x; x.f = f;
    unsigned r = x.u + 0x7fffu + ((x.u >> 16) & 1u);   // RTNE
    return (unsigned short)(r >> 16);
}
__device__ __forceinline__ uint umax2(uint a, uint b) { return a > b ? a : b; }
__device__ __forceinline__ uint umin2(uint a, uint b) { return a < b ? a : b; }
__device__ __forceinline__ int swz(int u, int r) {    // 16B-unit XOR swizzle
    return (u & 24) | ((u ^ r) & 7);
}

// One wave per row: l2-normalize; emit fp32 (optional) + bf16 copies.
__global__ __launch_bounds__(256) void normalize_kernel(
        const float* __restrict__ src, float* __restrict__ dst,
        unsigned short* __restrict__ dstb, int nrows) {
    int wave = threadIdx.x >> 6, lane = threadIdx.x & 63;
    int r = blockIdx.x * 4 + wave;
    if (r >= nrows) return;
    float4 v = *(const float4*)(src + (size_t)r * DIM + lane * 4);
    float ss = v.x * v.x + v.y * v.y + v.z * v.z + v.w * v.w;
    #pragma unroll
    for (int o = 32; o; o >>= 1) ss += __shfl_xor(ss, o);
    float rinv = 1.0f / fmaxf(sqrtf(ss), 1e-12f);
    float4 o4; o4.x = v.x * rinv; o4.y = v.y * rinv; o4.z = v.z * rinv; o4.w = v.w * rinv;
    if (dst) *(float4*)(dst + (size_t)r * DIM + lane * 4) = o4;
    ushort4 b; b.x = f2b(o4.x); b.y = f2b(o4.y); b.z = f2b(o4.z); b.w = f2b(o4.w);
    *(ushort4*)(dstb + (size_t)r * DIM + lane * 4) = b;
}

// Scan: block = 256 rows x one quarter (2048 codes). Wave w owns rows
// [w*64, w*64+64) as 4 MFMA row-groups sharing each B fragment. 32-code tiles:
// 16 ds_read_b128 -> 64 MFMA per tile, 1 barrier. B staged to LDS through VGPRs
// (3-stage pipeline, double buffer), XOR-swizzled layout (R6-proven).
// Top-2 keys per (row, residue16): key = fp32bits(score+2) & ~0x1FF | tile9.
__global__ __launch_bounds__(256, 2) void scan_kernel(
        const unsigned short* __restrict__ zfb,
        const unsigned short* __restrict__ cbb,
        uint* __restrict__ cand) {   // [row][128] = [row][4quarter][16res][2]
    __shared__ __align__(16) char lds[2 * BUF_B];
    int tid = threadIdx.x, w = tid >> 6, lane = tid & 63;
    int m = lane & 15, g = lane >> 4;
    int rb = blockIdx.x >> 2, quarter = blockIdx.x & 3;
    int r0 = rb * 256 + w * 64;
    const v4f C2 = {2.f, 2.f, 2.f, 2.f};

    // A fragments: A[m][k], k = c*32 + g*8 + j ; 4 row-groups of 16
    v8s a[4][8];
    #pragma unroll
    for (int h = 0; h < 4; ++h) {
        const unsigned short* ap = zfb + (size_t)(r0 + h * 16 + m) * DIM + g * 8;
        #pragma unroll
        for (int c = 0; c < 8; ++c) a[h][c] = *(const v8s*)(ap + c * 32);
    }

    // Staging: part i -> chunk q = 4w+i = code-row pair {2q, 2q+1}; 16 chunks/tile.
    const char* cb_base = (const char*)cbb + (size_t)quarter * 2048 * 512;
    const char* gp[4];
    int wo[4];
    #pragma unroll
    for (int i = 0; i < 4; ++i) {
        int q = 4 * w + i;
        int rr = 2 * q + (lane >> 5);
        int u = lane & 31;
        gp[i] = cb_base + q * 1024 + lane * 16;
        wo[i] = rr * 512 + swz(u, rr) * 16;
    }
    // ds_read offsets per K-chunk c (sub-tile 0; sub-tile 1 = +8192)
    int roff[8];
    #pragma unroll
    for (int c = 0; c < 8; ++c)
        roff[c] = m * 512 + swz(4 * c + g, m) * 16;

    // 3-stage pipeline prologue: load tile0 -> write buf0 -> load tile1
    uint4 st[4];
    #pragma unroll
    for (int i = 0; i < 4; ++i) { st[i] = *(const uint4*)gp[i]; gp[i] += BUF_B; }
    #pragma unroll
    for (int i = 0; i < 4; ++i) *(uint4*)(lds + wo[i]) = st[i];
    #pragma unroll
    for (int i = 0; i < 4; ++i) { st[i] = *(const uint4*)gp[i]; gp[i] += BUF_B; }

    uint top1[16], top2[16];
    #pragma unroll
    for (int i = 0; i < 16; ++i) { top1[i] = 0u; top2[i] = 0u; }

    for (int t = 0; t < NT; ++t) {
        __syncthreads();   // tile t's writes (all waves) visible; t-1 reads done
        if (t + 1 < NT) {
            char* nbuf = lds + ((t + 1) & 1) * BUF_B;
            #pragma unroll
            for (int i = 0; i < 4; ++i) *(uint4*)(nbuf + wo[i]) = st[i];
            if (t + 2 < NT) {
                #pragma unroll
                for (int i = 0; i < 4; ++i) { st[i] = *(const uint4*)gp[i]; gp[i] += BUF_B; }
            }
        }
        const char* cbuf = lds + (t & 1) * BUF_B;
        v4f acc[2][4];
        #pragma unroll
        for (int s2 = 0; s2 < 2; ++s2) {
            #pragma unroll
            for (int c = 0; c < 8; ++c) {
                v8s b = *(const v8s*)(cbuf + s2 * 8192 + roff[c]);
                #pragma unroll
                for (int h = 0; h < 4; ++h) {
                    v4f cin = (c == 0) ? C2 : acc[s2][h];   // C=const: no init movs
                    acc[s2][h] = __builtin_amdgcn_mfma_f32_16x16x32_bf16(a[h][c], b, cin, 0, 0, 0);
                }
            }
        }
        #pragma unroll
        for (int s2 = 0; s2 < 2; ++s2) {
            uint gt = (uint)(quarter * 128 + 2 * t + s2);   // 9-bit global tile id
            #pragma unroll
            for (int i = 0; i < 16; ++i) {
                float sc = acc[s2][i >> 2][i & 3];          // in [1,3]: bits sortable
                uint key = (__float_as_uint(sc) & 0xFFFFFE00u) | gt;  // v_and_or_b32
                uint old1 = top1[i];
                top1[i] = umax2(old1, key);
                top2[i] = umax2(top2[i], umin2(old1, key));
            }
        }
    }

    // C/D layout: row = g*4 + q, col(residue) = m
    #pragma unroll
    for (int i = 0; i < 16; ++i) {
        int h = i >> 2, q = i & 3;
        int row = r0 + h * 16 + g * 4 + q;
        uint2 v; v.x = top1[i]; v.y = top2[i];
        *(uint2*)(cand + (size_t)row * 128 + (quarter * 16 + m) * 2) = v;
    }
}

// One wave per row. Prune 128 candidates at margin 0.05 (worst-case bf16 key
// skew 0.0196), compact survivors via ballot-prefix into wave-private LDS.
// Lane l computes a full fp32 dot for survivor l (z row broadcast from LDS).
// fp64 wave-rescore only for fp32-near-ties (2e-4 >> fp32 err ~5e-6); unique
// near-min is provably exact. First-index tie-break throughout.
__global__ __launch_bounds__(256) void rescore_kernel(
        const float* __restrict__ x, const float* __restrict__ cb,
        const uint* __restrict__ cand, float* __restrict__ out,
        float* __restrict__ out_idx, double* __restrict__ lossp) {
    __shared__ float s_z[4][256];
    __shared__ int s_surv[4][128];
    int w = threadIdx.x >> 6, lane = threadIdx.x & 63;
    int r = blockIdx.x * 4 + w;
    float4 xv = *(const float4*)(x + (size_t)r * DIM + lane * 4);
    float ss = xv.x * xv.x + xv.y * xv.y + xv.z * xv.z + xv.w * xv.w;
    #pragma unroll
    for (int o = 32; o; o >>= 1) ss += __shfl_xor(ss, o);
    float rinv = 1.0f / fmaxf(sqrtf(ss), 1e-12f);
    float4 z4; z4.x = xv.x * rinv; z4.y = xv.y * rinv; z4.z = xv.z * rinv; z4.w = xv.w * rinv;
    *(float4*)(&s_z[w][lane * 4]) = z4;

    uint2 kk = *(const uint2*)(cand + (size_t)r * 128 + lane * 2);
    float kf0 = __uint_as_float(kk.x & 0xFFFFFE00u);
    float kf1 = __uint_as_float(kk.y & 0xFFFFFE00u);
    float kmax = fmaxf(kf0, kf1);
    #pragma unroll
    for (int o = 32; o; o >>= 1) kmax = fmaxf(kmax, __shfl_xor(kmax, o));
    float thr = kmax - 0.050f;
    bool p0 = kf0 >= thr, p1 = kf1 >= thr;
    ull m0 = __ballot(p0), m1 = __ballot(p1);
    ull lt = (1ull << lane) - 1ull;
    int ns0 = __popcll(m0);
    int ns = ns0 + __popcll(m1);
    int code0 = (int)(kk.x & 0x1FFu) * 16 + (lane & 15);
    int code1 = (int)(kk.y & 0x1FFu) * 16 + (lane & 15);
    if (p0) s_surv[w][__popcll(m0 & lt)] = code0;
    if (p1) s_surv[w][ns0 + __popcll(m1 & lt)] = code1;
    // wave-private LDS: same-wave DS ops execute in order; no barrier needed.

    bool act = lane < ns;
    int j = s_surv[w][act ? lane : 0];
    float d1; int jj;
    {
        const float* cp = cb + (size_t)j * DIM;
        float scc = 0.f, scz = 0.f;
        #pragma unroll 8
        for (int i = 0; i < 64; ++i) {
            float4 c4 = *(const float4*)(cp + i * 4);
            float4 zq = *(const float4*)(&s_z[w][i * 4]);
            scc += c4.x * c4.x + c4.y * c4.y + c4.z * c4.z + c4.w * c4.w;
            scz += c4.x * zq.x + c4.y * zq.y + c4.z * zq.z + c4.w * zq.w;
        }
        d1 = act ? (scc - 2.f * scz) : 3.0e38f;
        jj = act ? j : 0x7fffffff;
    }
    if (ns > 64) {   // effectively never for this data; correctness fallback
        bool act2 = (lane + 64) < ns;
        int j2 = s_surv[w][act2 ? (lane + 64) : 0];
        const float* cp = cb + (size_t)j2 * DIM;
        float scc = 0.f, scz = 0.f;
        #pragma unroll 8
        for (int i = 0; i < 64; ++i) {
            float4 c4 = *(const float4*)(cp + i * 4);
            float4 zq = *(const float4*)(&s_z[w][i * 4]);
            scc += c4.x * c4.x + c4.y * c4.y + c4.z * c4.z + c4.w * c4.w;
            scz += c4.x * zq.x + c4.y * zq.y + c4.z * zq.z + c4.w * zq.w;
        }
        float d2 = act2 ? (scc - 2.f * scz) : 3.0e38f;
        if (d2 < d1 || (d2 == d1 && j2 < jj)) { d1 = d2; jj = j2; }
    }
    float dmin = d1;
    #pragma unroll
    for (int o = 32; o; o >>= 1) dmin = fminf(dmin, __shfl_xor(dmin, o));
    ull nearm = __ballot(act && d1 <= dmin + 2e-4f);
    int bestj;
    if (__popcll(nearm) == 1) {
        bestj = __shfl(jj, (int)__builtin_ctzll(nearm));   // provably exact
    } else {
        double bestd = 1e300; bestj = 0x7fffffff;
        while (nearm) {
            int b = (int)__builtin_ctzll(nearm); nearm &= nearm - 1;
            int jc = __shfl(jj, b);
            float4 c4 = *(const float4*)(cb + (size_t)jc * DIM + lane * 4);
            double p = (double)c4.x * ((double)c4.x - 2.0 * (double)z4.x)
                     + (double)c4.y * ((double)c4.y - 2.0 * (double)z4.y)
                     + (double)c4.z * ((double)c4.z - 2.0 * (double)z4.z)
                     + (double)c4.w * ((double)c4.w - 2.0 * (double)z4.w);
            #pragma unroll
            for (int o = 32; o; o >>= 1) p += __shfl_xor(p, o);
            if (p < bestd || (p == bestd && jc < bestj)) { bestd = p; bestj = jc; }
        }
    }
    float4 c4 = *(const float4*)(cb + (size_t)bestj * DIM + lane * 4);
    *(float4*)(out + (size_t)r * DIM + lane * 4) = c4;
    double dx = (double)c4.x - (double)z4.x, dy = (double)c4.y - (double)z4.y;
    double dz = (double)c4.z - (double)z4.z, dw = (double)c4.w - (double)z4.w;
    double lp = dx * dx + dy * dy + dz * dz + dw * dw;
    #pragma unroll
    for (int o = 32; o; o >>= 1) lp += __shfl_xor(lp, o);
    if (lane == 0) { lossp[r] = lp; out_idx[r] = (float)bestj; }
}

__global__ __launch_bounds__(256) void loss_kernel(
        const double* __restrict__ lossp, float* __restrict__ out) {
    __shared__ double sm[256];
    double s = 0.0;
    for (int i = threadIdx.x; i < M_ROWS; i += 256) s += lossp[i];
    sm[threadIdx.x] = s;
    __syncthreads();
    for (int o = 128; o; o >>= 1) {
        if ((int)threadIdx.x < o) sm[threadIdx.x] += sm[threadIdx.x + o];
        __syncthreads();
    }
    if (threadIdx.x == 0)
        out[0] = (float)(sm[0] * (1.25 / (double)(M_ROWS * DIM)));  // (BETA+1)*mean
}

extern "C" void kernel_launch(void* const* d_in, const int* in_sizes, int n_in,
                              void* d_out, int out_size, void* d_ws, size_t ws_size,
                              hipStream_t stream) {
    const float* x   = (const float*)d_in[0];   // 32*1024*256
    const float* emb = (const float*)d_in[1];   // 8192*256
    float* out = (float*)d_out;
    char* ws = (char*)d_ws;

    float*          cb    = (float*)(ws);                          // 8 MB
    unsigned short* cbb   = (unsigned short*)(ws + (8u  << 20));   // 4 MB
    unsigned short* zfb   = (unsigned short*)(ws + (12u << 20));   // 16 MB
    uint*           cand  = (uint*)(ws + (28u << 20));             // 16 MB
    double*         lossp = (double*)(ws + (44u << 20));           // 256 KB

    normalize_kernel<<<N_CODES / 4, 256, 0, stream>>>(emb, cb, cbb, N_CODES);
    normalize_kernel<<<M_ROWS / 4, 256, 0, stream>>>(x, nullptr, zfb, M_ROWS);
    scan_kernel<<<512, 256, 0, stream>>>(zfb, cbb, cand);
    rescore_kernel<<<M_ROWS / 4, 256, 0, stream>>>(x, cb, cand,
                                                   out, out + ((size_t)M_ROWS * DIM + 1), lossp);
    loss_kernel<<<1, 256, 0, stream>>>(lossp, out + (size_t)M_ROWS * DIM);
}